// Round 4
// baseline (416.404 us; speedup 1.0000x reference)
//
#include <hip/hip_runtime.h>

#define N_NODES 20000
#define N_EDGES 640000
#define IN_F    2000
#define C_OUT   64
#define HC      256   // HEADS * C_OUT
#define NEG     0.2f

// ---------------- CSR build ----------------

__global__ void k_hist(const int* __restrict__ dst, int* __restrict__ counts) {
    int e = blockIdx.x * blockDim.x + threadIdx.x;
    if (e < N_EDGES) atomicAdd(&counts[dst[e]], 1);
}

// single block, 1024 threads: exclusive scan of counts[20000] -> offsets, cursor
__global__ void k_scan(const int* __restrict__ counts, int* __restrict__ offsets,
                       int* __restrict__ cursor) {
    __shared__ int wsum[16];
    __shared__ int carry_sh;
    int tid = threadIdx.x;
    int lane = tid & 63, wid = tid >> 6;
    if (tid == 0) carry_sh = 0;
    __syncthreads();
    for (int start = 0; start < N_NODES; start += 1024) {
        int i = start + tid;
        int v = (i < N_NODES) ? counts[i] : 0;
        int s = v;
        #pragma unroll
        for (int d = 1; d < 64; d <<= 1) {
            int t = __shfl_up(s, d, 64);
            if (lane >= d) s += t;
        }
        if (lane == 63) wsum[wid] = s;
        __syncthreads();
        if (tid < 64) {
            int ws = (lane < 16) ? wsum[lane] : 0;
            #pragma unroll
            for (int d = 1; d < 16; d <<= 1) {
                int t = __shfl_up(ws, d, 64);
                if (lane >= d) ws += t;
            }
            if (lane < 16) wsum[lane] = ws;
        }
        __syncthreads();
        int carry = carry_sh;
        int wbase = (wid > 0) ? wsum[wid - 1] : 0;
        int excl = carry + wbase + (s - v);
        if (i < N_NODES) { offsets[i] = excl; cursor[i] = excl; }
        __syncthreads();
        if (tid == 0) carry_sh = carry + wsum[15];
        __syncthreads();
    }
    if (tid == 0) offsets[N_NODES] = carry_sh;
}

__global__ void k_scatter(const int* __restrict__ src, const int* __restrict__ dst,
                          int* __restrict__ cursor, int* __restrict__ ssrc) {
    int e = blockIdx.x * blockDim.x + threadIdx.x;
    if (e < N_EDGES) {
        int d = dst[e];
        int p = atomicAdd(&cursor[d], 1);
        ssrc[p] = src[e];
    }
}

// ---------------- h = x @ W_ae + b_ae  (fp32 tiled) ----------------
// BM=32 rows x 64 cols per block; KT=16. 20000/32 = 625 blocks exactly.

__global__ __launch_bounds__(256) void k_gemm_h(
    const float* __restrict__ x, const float* __restrict__ W,
    const float* __restrict__ b, float* __restrict__ h) {
    __shared__ float As[32 * 20];   // stride 20 keeps float4 alignment + spreads banks
    __shared__ float Bs[16 * 64];
    int t = threadIdx.x;
    int row0 = blockIdx.x * 32;
    int tr = t >> 4, tc = t & 15;   // thread computes rows tr*2..+1, cols tc*4..+3
    float acc[2][4] = {{0,0,0,0},{0,0,0,0}};
    for (int k0 = 0; k0 < IN_F; k0 += 16) {
        if (t < 128) {
            int r = t >> 2, kv = (t & 3) << 2;
            float4 a4 = *(const float4*)&x[(size_t)(row0 + r) * IN_F + k0 + kv];
            *(float4*)&As[r * 20 + kv] = a4;
        }
        {
            int kk = t >> 4, c4 = (t & 15) << 2;
            float4 b4 = *(const float4*)&W[(size_t)(k0 + kk) * C_OUT + c4];
            *(float4*)&Bs[kk * 64 + c4] = b4;
        }
        __syncthreads();
        #pragma unroll
        for (int kk = 0; kk < 16; ++kk) {
            float a0 = As[(tr * 2 + 0) * 20 + kk];
            float a1 = As[(tr * 2 + 1) * 20 + kk];
            float4 b4 = *(float4*)&Bs[kk * 64 + tc * 4];
            acc[0][0] += a0 * b4.x; acc[0][1] += a0 * b4.y;
            acc[0][2] += a0 * b4.z; acc[0][3] += a0 * b4.w;
            acc[1][0] += a1 * b4.x; acc[1][1] += a1 * b4.y;
            acc[1][2] += a1 * b4.z; acc[1][3] += a1 * b4.w;
        }
        __syncthreads();
    }
    float4 bb = *(const float4*)&b[tc * 4];
    #pragma unroll
    for (int i = 0; i < 2; ++i) {
        float4 o = { acc[i][0] + bb.x, acc[i][1] + bb.y,
                     acc[i][2] + bb.z, acc[i][3] + bb.w };
        *(float4*)&h[(size_t)(row0 + tr * 2 + i) * C_OUT + tc * 4] = o;
    }
}

// ---------------- xl = h@Wl+bl, xr = h@Wr+br ----------------
// one wave per node (4 nodes per 256-thread block); lane holds 4 of 256 outputs.

__global__ __launch_bounds__(256) void k_xlxr(
    const float* __restrict__ h, const float* __restrict__ Wl, const float* __restrict__ bl,
    const float* __restrict__ Wr, const float* __restrict__ br,
    float* __restrict__ xl, float* __restrict__ xr) {
    int wid = threadIdx.x >> 6, lane = threadIdx.x & 63;
    int node = blockIdx.x * 4 + wid;
    float hv = h[(size_t)node * C_OUT + lane];
    float4 al = *(const float4*)&bl[lane * 4];
    float4 ar = *(const float4*)&br[lane * 4];
    #pragma unroll 4
    for (int k = 0; k < 64; ++k) {
        float hk = __shfl(hv, k, 64);
        float4 wl = *(const float4*)&Wl[k * HC + lane * 4];
        float4 wr = *(const float4*)&Wr[k * HC + lane * 4];
        al.x += hk * wl.x; al.y += hk * wl.y; al.z += hk * wl.z; al.w += hk * wl.w;
        ar.x += hk * wr.x; ar.y += hk * wr.y; ar.z += hk * wr.z; ar.w += hk * wr.w;
    }
    *(float4*)&xl[(size_t)node * HC + lane * 4] = al;
    *(float4*)&xr[(size_t)node * HC + lane * 4] = ar;
}

// ---------------- fused attention + linear + residual + LayerNorm ----------------
// one wave per node; lane = channels 4l..4l+3 of the 256 concat channels.
// head(lane) = lane/16; per-head logit reduce over 16-lane groups via shfl_xor.

__global__ __launch_bounds__(256) void k_attn(
    const float* __restrict__ xl, const float* __restrict__ xr,
    const float* __restrict__ h, const int* __restrict__ offsets,
    const int* __restrict__ ssrc, const float* __restrict__ att,
    const float* __restrict__ b_conv, const float* __restrict__ W_lin,
    const float* __restrict__ b_lin, const float* __restrict__ ln_w,
    const float* __restrict__ ln_b, float* __restrict__ out) {
    __shared__ float sh[4][HC];
    int wid = threadIdx.x >> 6, lane = threadIdx.x & 63;
    int node = blockIdx.x * 4 + wid;

    const float4 xri  = *(const float4*)&xr[(size_t)node * HC + lane * 4];
    const float4 att4 = *(const float4*)&att[lane * 4];
    float4 acc = {0.f, 0.f, 0.f, 0.f};
    float denom = 0.f;

    auto process = [&](int j) {
        float4 xlj = *(const float4*)&xl[(size_t)j * HC + lane * 4];
        float4 g;
        g.x = xlj.x + xri.x; g.x = g.x > 0.f ? g.x : NEG * g.x;
        g.y = xlj.y + xri.y; g.y = g.y > 0.f ? g.y : NEG * g.y;
        g.z = xlj.z + xri.z; g.z = g.z > 0.f ? g.z : NEG * g.z;
        g.w = xlj.w + xri.w; g.w = g.w > 0.f ? g.w : NEG * g.w;
        float p = g.x * att4.x + g.y * att4.y + g.z * att4.z + g.w * att4.w;
        // reduce over the 16 lanes of this head
        p += __shfl_xor(p, 1); p += __shfl_xor(p, 2);
        p += __shfl_xor(p, 4); p += __shfl_xor(p, 8);
        float ex = __expf(p);   // logits are O(1): no max-subtraction needed
        denom += ex;
        acc.x += ex * xlj.x; acc.y += ex * xlj.y;
        acc.z += ex * xlj.z; acc.w += ex * xlj.w;
    };

    process(node);  // self loop
    int s0 = offsets[node], s1 = offsets[node + 1];
    for (int base = s0; base < s1; base += 64) {
        int cnt = min(64, s1 - base);
        int jv = (base + lane < s1) ? ssrc[base + lane] : 0;
        for (int t = 0; t < cnt; ++t) {
            int j = __shfl(jv, t, 64);
            process(j);
        }
    }

    float inv = 1.f / denom;
    float4 bc = *(const float4*)&b_conv[lane * 4];
    float4 ov = { acc.x * inv + bc.x, acc.y * inv + bc.y,
                  acc.z * inv + bc.z, acc.w * inv + bc.w };
    *(float4*)&sh[wid][lane * 4] = ov;
    __syncthreads();

    // a = relu(ov @ W_lin + b_lin); lane computes output channel `lane`
    float s = b_lin[lane];
    #pragma unroll 8
    for (int k = 0; k < HC; k += 4) {
        float4 o4 = *(float4*)&sh[wid][k];
        s += o4.x * W_lin[(k + 0) * C_OUT + lane];
        s += o4.y * W_lin[(k + 1) * C_OUT + lane];
        s += o4.z * W_lin[(k + 2) * C_OUT + lane];
        s += o4.w * W_lin[(k + 3) * C_OUT + lane];
    }
    float a = s > 0.f ? s : 0.f;
    float y = a + h[(size_t)node * C_OUT + lane];

    // LayerNorm over 64 channels (full-wave reduce)
    float m = y;
    m += __shfl_xor(m, 1);  m += __shfl_xor(m, 2);  m += __shfl_xor(m, 4);
    m += __shfl_xor(m, 8);  m += __shfl_xor(m, 16); m += __shfl_xor(m, 32);
    m *= (1.f / 64.f);
    float d = y - m;
    float v2 = d * d;
    v2 += __shfl_xor(v2, 1);  v2 += __shfl_xor(v2, 2);  v2 += __shfl_xor(v2, 4);
    v2 += __shfl_xor(v2, 8);  v2 += __shfl_xor(v2, 16); v2 += __shfl_xor(v2, 32);
    v2 *= (1.f / 64.f);
    out[(size_t)node * C_OUT + lane] = ln_w[lane] * d * rsqrtf(v2 + 1e-12f) + ln_b[lane];
}

// ---------------- launch ----------------

extern "C" void kernel_launch(void* const* d_in, const int* in_sizes, int n_in,
                              void* d_out, int out_size, void* d_ws, size_t ws_size,
                              hipStream_t stream) {
    const float* x     = (const float*)d_in[0];
    const int*   ei    = (const int*)  d_in[1];
    const float* W_ae  = (const float*)d_in[2];
    const float* b_ae  = (const float*)d_in[3];
    const float* Wl    = (const float*)d_in[4];
    const float* bl    = (const float*)d_in[5];
    const float* Wr    = (const float*)d_in[6];
    const float* br    = (const float*)d_in[7];
    const float* att   = (const float*)d_in[8];
    const float* b_conv= (const float*)d_in[9];
    const float* W_lin = (const float*)d_in[10];
    const float* b_lin = (const float*)d_in[11];
    const float* ln_w  = (const float*)d_in[12];
    const float* ln_b  = (const float*)d_in[13];
    float* out = (float*)d_out;
    const int* src = ei;
    const int* dst = ei + N_EDGES;

    char* ws = (char*)d_ws;
    size_t off = 0;
    auto alloc = [&](size_t bytes) {
        void* p = ws + off;
        off = (off + bytes + 255) & ~(size_t)255;
        return p;
    };
    float* h       = (float*)alloc((size_t)N_NODES * C_OUT * 4);
    float* xl      = (float*)alloc((size_t)N_NODES * HC * 4);
    float* xr      = (float*)alloc((size_t)N_NODES * HC * 4);
    int*   counts  = (int*)  alloc((size_t)N_NODES * 4);
    int*   offsets = (int*)  alloc((size_t)(N_NODES + 1) * 4);
    int*   cursor  = (int*)  alloc((size_t)N_NODES * 4);
    int*   ssrc    = (int*)  alloc((size_t)N_EDGES * 4);

    hipMemsetAsync(counts, 0, (size_t)N_NODES * 4, stream);
    k_hist   <<<(N_EDGES + 255) / 256, 256, 0, stream>>>(dst, counts);
    k_scan   <<<1, 1024, 0, stream>>>(counts, offsets, cursor);
    k_scatter<<<(N_EDGES + 255) / 256, 256, 0, stream>>>(src, dst, cursor, ssrc);
    k_gemm_h <<<N_NODES / 32, 256, 0, stream>>>(x, W_ae, b_ae, h);
    k_xlxr   <<<N_NODES / 4, 256, 0, stream>>>(h, Wl, bl, Wr, br, xl, xr);
    k_attn   <<<N_NODES / 4, 256, 0, stream>>>(xl, xr, h, offsets, ssrc, att,
                                               b_conv, W_lin, b_lin, ln_w, ln_b, out);
}

// Round 6
// 287.184 us; speedup vs baseline: 1.4500x; 1.4500x over previous
//
#include <hip/hip_runtime.h>

#define N_NODES 20000
#define N_EDGES 640000
#define IN_F    2000
#define KPAD    2048
#define C_OUT   64
#define HC      256   // HEADS * C_OUT
#define NEG     0.2f

typedef __attribute__((ext_vector_type(4))) float f32x4;
typedef __attribute__((ext_vector_type(8))) short bf16x8;

__device__ inline unsigned short f2bf(float f) {
    unsigned u = __float_as_uint(f);
    return (unsigned short)((u + 0x7FFFu + ((u >> 16) & 1u)) >> 16);
}

// ---------------- CSR build ----------------

__global__ void k_hist(const int* __restrict__ dst, int* __restrict__ counts) {
    int e = blockIdx.x * blockDim.x + threadIdx.x;
    if (e < N_EDGES) atomicAdd(&counts[dst[e]], 1);
}

__global__ void k_scan(const int* __restrict__ counts, int* __restrict__ offsets,
                       int* __restrict__ cursor) {
    __shared__ int wsum[16];
    __shared__ int carry_sh;
    int tid = threadIdx.x;
    int lane = tid & 63, wid = tid >> 6;
    if (tid == 0) carry_sh = 0;
    __syncthreads();
    for (int start = 0; start < N_NODES; start += 1024) {
        int i = start + tid;
        int v = (i < N_NODES) ? counts[i] : 0;
        int s = v;
        #pragma unroll
        for (int d = 1; d < 64; d <<= 1) {
            int t = __shfl_up(s, d, 64);
            if (lane >= d) s += t;
        }
        if (lane == 63) wsum[wid] = s;
        __syncthreads();
        if (tid < 64) {
            int ws = (lane < 16) ? wsum[lane] : 0;
            #pragma unroll
            for (int d = 1; d < 16; d <<= 1) {
                int t = __shfl_up(ws, d, 64);
                if (lane >= d) ws += t;
            }
            if (lane < 16) wsum[lane] = ws;
        }
        __syncthreads();
        int carry = carry_sh;
        int wbase = (wid > 0) ? wsum[wid - 1] : 0;
        int excl = carry + wbase + (s - v);
        if (i < N_NODES) { offsets[i] = excl; cursor[i] = excl; }
        __syncthreads();
        if (tid == 0) carry_sh = carry + wsum[15];
        __syncthreads();
    }
    if (tid == 0) offsets[N_NODES] = carry_sh;
}

__global__ void k_scatter(const int* __restrict__ src, const int* __restrict__ dst,
                          int* __restrict__ cursor, int* __restrict__ ssrc) {
    int e = blockIdx.x * blockDim.x + threadIdx.x;
    if (e < N_EDGES) {
        int d = dst[e];
        int p = atomicAdd(&cursor[d], 1);
        ssrc[p] = src[e];
    }
}

// ---------------- Wt = W_ae^T in bf16, K padded to 2048 ----------------

__global__ void k_wt(const float* __restrict__ W, unsigned short* __restrict__ Wt) {
    int idx = blockIdx.x * 256 + threadIdx.x;   // 64*2048 = 131072 total
    int n = idx >> 11;
    int k = idx & 2047;
    float v = (k < IN_F) ? W[(size_t)k * C_OUT + n] : 0.f;
    Wt[(size_t)n * KPAD + k] = f2bf(v);
}

// ---------------- h = x @ W_ae + b_ae  (bf16 MFMA, fused fp32->bf16) --------
// BM=32, BN=64, BK=64; 625 blocks x 256 threads (4 waves: wr=rows, wc=col-half).
// LDS layout: [row][64 bf16] = 8 slots of 16B; slot XOR-swizzled by (row&7).

__global__ __launch_bounds__(256) void k_gemm_h(
    const float* __restrict__ x, const unsigned short* __restrict__ Wt,
    const float* __restrict__ b, float* __restrict__ h) {
    __shared__ unsigned short Asw[32 * 64];   // 4 KB
    __shared__ unsigned short Bsw[64 * 64];   // 8 KB
    int t = threadIdx.x;
    int lane = t & 63, wid = t >> 6;
    int wr = wid >> 1, wc = wid & 1;
    int row0 = blockIdx.x * 32;

    int a_row = t & 31, a_half = t >> 5;     // A stage: 8 bf16 (1 slot) per thread
    int b_n = t >> 2, b_kq = t & 3;          // B stage: 16 bf16 (2 slots) per thread

    int rA = wr * 16 + (lane & 15);          // this lane's A row in LDS
    int kchunk = lane >> 4;                  // 0..3
    f32x4 acc0 = {0.f, 0.f, 0.f, 0.f}, acc1 = {0.f, 0.f, 0.f, 0.f};

    for (int k0 = 0; k0 < KPAD; k0 += 64) {
        // stage A: x[row0+a_row][k0 + a_half*8 .. +7] -> bf16 slot
        {
            uint4 wv = {0u, 0u, 0u, 0u};
            int kbase = k0 + a_half * 8;
            if (kbase < IN_F) {   // 2000 % 8 == 0: group fully valid or fully pad
                const float* src = &x[(size_t)(row0 + a_row) * IN_F + kbase];
                float4 f0 = *(const float4*)src;
                float4 f1 = *(const float4*)(src + 4);
                wv.x = (unsigned)f2bf(f0.x) | ((unsigned)f2bf(f0.y) << 16);
                wv.y = (unsigned)f2bf(f0.z) | ((unsigned)f2bf(f0.w) << 16);
                wv.z = (unsigned)f2bf(f1.x) | ((unsigned)f2bf(f1.y) << 16);
                wv.w = (unsigned)f2bf(f1.z) | ((unsigned)f2bf(f1.w) << 16);
            }
            int slot = a_half ^ (a_row & 7);
            *(uint4*)((char*)Asw + a_row * 128 + slot * 16) = wv;
        }
        // stage B: Wt[b_n][k0 + b_kq*16 .. +15] (already bf16, padded)
        {
            const uint4* src = (const uint4*)&Wt[(size_t)b_n * KPAD + k0 + b_kq * 16];
            uint4 w0 = src[0], w1 = src[1];
            int s0 = (b_kq * 2) ^ (b_n & 7);
            int s1 = (b_kq * 2 + 1) ^ (b_n & 7);
            *(uint4*)((char*)Bsw + b_n * 128 + s0 * 16) = w0;
            *(uint4*)((char*)Bsw + b_n * 128 + s1 * 16) = w1;
        }
        __syncthreads();
        #pragma unroll
        for (int ks = 0; ks < 2; ++ks) {
            int aslot = (ks * 4 + kchunk) ^ (rA & 7);
            bf16x8 af = *(bf16x8*)((char*)Asw + rA * 128 + aslot * 16);
            {
                int cb = wc * 32 + 0 * 16 + (lane & 15);
                int bslot = (ks * 4 + kchunk) ^ (cb & 7);
                bf16x8 bfr = *(bf16x8*)((char*)Bsw + cb * 128 + bslot * 16);
                acc0 = __builtin_amdgcn_mfma_f32_16x16x32_bf16(af, bfr, acc0, 0, 0, 0);
            }
            {
                int cb = wc * 32 + 1 * 16 + (lane & 15);
                int bslot = (ks * 4 + kchunk) ^ (cb & 7);
                bf16x8 bfr = *(bf16x8*)((char*)Bsw + cb * 128 + bslot * 16);
                acc1 = __builtin_amdgcn_mfma_f32_16x16x32_bf16(af, bfr, acc1, 0, 0, 0);
            }
        }
        __syncthreads();
    }
    // epilogue: C/D mapping col=lane&15, row=(lane>>4)*4+r (verified m89/m91)
    int ci = (lane >> 4) * 4;
    int cj = lane & 15;
    #pragma unroll
    for (int nt = 0; nt < 2; ++nt) {
        f32x4 a = nt ? acc1 : acc0;
        int col = wc * 32 + nt * 16 + cj;
        float bb = b[col];
        #pragma unroll
        for (int r = 0; r < 4; ++r) {
            int grow = row0 + wr * 16 + ci + r;
            h[(size_t)grow * C_OUT + col] = a[r] + bb;
        }
    }
}

// ---------------- xl|xr = h @ [Wl|Wr] + [bl|br]  (fp32 tiled, W in LDS) -----
// grid = 313 M-blocks x 4 N-blocks; BM=64 nodes, BN=128 of 512 concat cols.

__global__ __launch_bounds__(256) void k_xlxr2(
    const float* __restrict__ h, const float* __restrict__ Wl, const float* __restrict__ bl,
    const float* __restrict__ Wr, const float* __restrict__ br,
    float* __restrict__ xl, float* __restrict__ xr) {
    __shared__ float hs[64][68];      // ~17.4 KB, +4 pad
    __shared__ float Ws[64][128];     // 32 KB
    int t = threadIdx.x;
    int mb = blockIdx.x >> 2, nb = blockIdx.x & 3;
    int node0 = mb * 64;
    const float* Wsrc = (nb < 2) ? (Wl + nb * 128) : (Wr + (nb - 2) * 128);
    const float* bsrc = (nb < 2) ? (bl + nb * 128) : (br + (nb - 2) * 128);
    float*       odst = (nb < 2) ? (xl + nb * 128) : (xr + (nb - 2) * 128);

    {   // stage h tile: thread = (row, quarter of 16 floats)
        int row = t >> 2, q = t & 3;
        int gnode = node0 + row; if (gnode >= N_NODES) gnode = N_NODES - 1;
        const float4* src = (const float4*)&h[(size_t)gnode * C_OUT + q * 16];
        *(float4*)&hs[row][q * 16 + 0]  = src[0];
        *(float4*)&hs[row][q * 16 + 4]  = src[1];
        *(float4*)&hs[row][q * 16 + 8]  = src[2];
        *(float4*)&hs[row][q * 16 + 12] = src[3];
    }
    {   // stage W tile: 2048 float4 / 256 threads = 8 each
        #pragma unroll
        for (int i = 0; i < 8; ++i) {
            int f = t + i * 256;
            int k = f >> 5, c4 = (f & 31) << 2;
            *(float4*)&Ws[k][c4] = *(const float4*)&Wsrc[(size_t)k * HC + c4];
        }
    }
    __syncthreads();

    int tr = t >> 5;   // 8 row-groups of 8 nodes
    int tc = t & 31;   // col group (x4 floats)
    float4 acc[8];
    float4 bv = *(const float4*)&bsrc[tc * 4];
    #pragma unroll
    for (int r = 0; r < 8; ++r) acc[r] = bv;

    for (int k4 = 0; k4 < 64; k4 += 4) {
        float4 w0 = *(float4*)&Ws[k4 + 0][tc * 4];
        float4 w1 = *(float4*)&Ws[k4 + 1][tc * 4];
        float4 w2 = *(float4*)&Ws[k4 + 2][tc * 4];
        float4 w3 = *(float4*)&Ws[k4 + 3][tc * 4];
        #pragma unroll
        for (int r = 0; r < 8; ++r) {
            float4 a = *(float4*)&hs[tr * 8 + r][k4];
            acc[r].x += a.x * w0.x + a.y * w1.x + a.z * w2.x + a.w * w3.x;
            acc[r].y += a.x * w0.y + a.y * w1.y + a.z * w2.y + a.w * w3.y;
            acc[r].z += a.x * w0.z + a.y * w1.z + a.z * w2.z + a.w * w3.z;
            acc[r].w += a.x * w0.w + a.y * w1.w + a.z * w2.w + a.w * w3.w;
        }
    }
    #pragma unroll
    for (int r = 0; r < 8; ++r) {
        int gnode = node0 + tr * 8 + r;
        if (gnode < N_NODES)
            *(float4*)&odst[(size_t)gnode * HC + tc * 4] = acc[r];
    }
}

// ---------------- fused attention + linear + residual + LayerNorm ----------------

__global__ __launch_bounds__(256) void k_attn(
    const float* __restrict__ xl, const float* __restrict__ xr,
    const float* __restrict__ h, const int* __restrict__ offsets,
    const int* __restrict__ ssrc, const float* __restrict__ att,
    const float* __restrict__ b_conv, const float* __restrict__ W_lin,
    const float* __restrict__ b_lin, const float* __restrict__ ln_w,
    const float* __restrict__ ln_b, float* __restrict__ out) {
    __shared__ float sh[4][HC];
    int wid = threadIdx.x >> 6, lane = threadIdx.x & 63;
    int node = blockIdx.x * 4 + wid;

    const float4 xri  = *(const float4*)&xr[(size_t)node * HC + lane * 4];
    const float4 att4 = *(const float4*)&att[lane * 4];
    float4 acc = {0.f, 0.f, 0.f, 0.f};
    float denom = 0.f;

    auto process = [&](int j) {
        float4 xlj = *(const float4*)&xl[(size_t)j * HC + lane * 4];
        float4 g;
        g.x = xlj.x + xri.x; g.x = g.x > 0.f ? g.x : NEG * g.x;
        g.y = xlj.y + xri.y; g.y = g.y > 0.f ? g.y : NEG * g.y;
        g.z = xlj.z + xri.z; g.z = g.z > 0.f ? g.z : NEG * g.z;
        g.w = xlj.w + xri.w; g.w = g.w > 0.f ? g.w : NEG * g.w;
        float p = g.x * att4.x + g.y * att4.y + g.z * att4.z + g.w * att4.w;
        p += __shfl_xor(p, 1); p += __shfl_xor(p, 2);
        p += __shfl_xor(p, 4); p += __shfl_xor(p, 8);
        float ex = __expf(p);   // logits are O(1): no max-subtraction needed
        denom += ex;
        acc.x += ex * xlj.x; acc.y += ex * xlj.y;
        acc.z += ex * xlj.z; acc.w += ex * xlj.w;
    };

    process(node);  // self loop
    int s0 = offsets[node], s1 = offsets[node + 1];
    for (int base = s0; base < s1; base += 64) {
        int cnt = min(64, s1 - base);
        int jv = (base + lane < s1) ? ssrc[base + lane] : 0;
        for (int t = 0; t < cnt; ++t) {
            int j = __shfl(jv, t, 64);
            process(j);
        }
    }

    float inv = 1.f / denom;
    float4 bc = *(const float4*)&b_conv[lane * 4];
    float4 ov = { acc.x * inv + bc.x, acc.y * inv + bc.y,
                  acc.z * inv + bc.z, acc.w * inv + bc.w };
    *(float4*)&sh[wid][lane * 4] = ov;
    __syncthreads();

    float s = b_lin[lane];
    #pragma unroll 8
    for (int k = 0; k < HC; k += 4) {
        float4 o4 = *(float4*)&sh[wid][k];
        s += o4.x * W_lin[(k + 0) * C_OUT + lane];
        s += o4.y * W_lin[(k + 1) * C_OUT + lane];
        s += o4.z * W_lin[(k + 2) * C_OUT + lane];
        s += o4.w * W_lin[(k + 3) * C_OUT + lane];
    }
    float a = s > 0.f ? s : 0.f;
    float y = a + h[(size_t)node * C_OUT + lane];

    float m = y;
    m += __shfl_xor(m, 1);  m += __shfl_xor(m, 2);  m += __shfl_xor(m, 4);
    m += __shfl_xor(m, 8);  m += __shfl_xor(m, 16); m += __shfl_xor(m, 32);
    m *= (1.f / 64.f);
    float d = y - m;
    float v2 = d * d;
    v2 += __shfl_xor(v2, 1);  v2 += __shfl_xor(v2, 2);  v2 += __shfl_xor(v2, 4);
    v2 += __shfl_xor(v2, 8);  v2 += __shfl_xor(v2, 16); v2 += __shfl_xor(v2, 32);
    v2 *= (1.f / 64.f);
    out[(size_t)node * C_OUT + lane] = ln_w[lane] * d * rsqrtf(v2 + 1e-12f) + ln_b[lane];
}

// ---------------- launch ----------------

extern "C" void kernel_launch(void* const* d_in, const int* in_sizes, int n_in,
                              void* d_out, int out_size, void* d_ws, size_t ws_size,
                              hipStream_t stream) {
    const float* x     = (const float*)d_in[0];
    const int*   ei    = (const int*)  d_in[1];
    const float* W_ae  = (const float*)d_in[2];
    const float* b_ae  = (const float*)d_in[3];
    const float* Wl    = (const float*)d_in[4];
    const float* bl    = (const float*)d_in[5];
    const float* Wr    = (const float*)d_in[6];
    const float* br    = (const float*)d_in[7];
    const float* att   = (const float*)d_in[8];
    const float* b_conv= (const float*)d_in[9];
    const float* W_lin = (const float*)d_in[10];
    const float* b_lin = (const float*)d_in[11];
    const float* ln_w  = (const float*)d_in[12];
    const float* ln_b  = (const float*)d_in[13];
    float* out = (float*)d_out;
    const int* src = ei;
    const int* dst = ei + N_EDGES;

    char* ws = (char*)d_ws;
    size_t off = 0;
    auto alloc = [&](size_t bytes) {
        void* p = ws + off;
        off = (off + bytes + 255) & ~(size_t)255;
        return p;
    };
    float* h       = (float*)alloc((size_t)N_NODES * C_OUT * 4);
    float* xl      = (float*)alloc((size_t)N_NODES * HC * 4);
    float* xr      = (float*)alloc((size_t)N_NODES * HC * 4);
    int*   counts  = (int*)  alloc((size_t)N_NODES * 4);
    int*   offsets = (int*)  alloc((size_t)(N_NODES + 1) * 4);
    int*   cursor  = (int*)  alloc((size_t)N_NODES * 4);
    int*   ssrc    = (int*)  alloc((size_t)N_EDGES * 4);
    unsigned short* Wt = (unsigned short*)alloc((size_t)C_OUT * KPAD * 2);

    hipMemsetAsync(counts, 0, (size_t)N_NODES * 4, stream);
    k_hist   <<<(N_EDGES + 255) / 256, 256, 0, stream>>>(dst, counts);
    k_scan   <<<1, 1024, 0, stream>>>(counts, offsets, cursor);
    k_scatter<<<(N_EDGES + 255) / 256, 256, 0, stream>>>(src, dst, cursor, ssrc);
    k_wt     <<<(C_OUT * KPAD) / 256, 256, 0, stream>>>(W_ae, Wt);
    k_gemm_h <<<N_NODES / 32, 256, 0, stream>>>(x, Wt, b_ae, h);
    k_xlxr2  <<<((N_NODES + 63) / 64) * 4, 256, 0, stream>>>(h, Wl, bl, Wr, br, xl, xr);
    k_attn   <<<N_NODES / 4, 256, 0, stream>>>(xl, xr, h, offsets, ssrc, att,
                                               b_conv, W_lin, b_lin, ln_w, ln_b, out);
}

// Round 7
// 228.334 us; speedup vs baseline: 1.8237x; 1.2577x over previous
//
#include <hip/hip_runtime.h>

#define N_NODES 20000
#define N_EDGES 640000
#define IN_F    2000
#define KPAD    2048
#define C_OUT   64
#define HC      256   // HEADS * C_OUT
#define NEG     0.2f
#define SCAN_B  79    // ceil(20000/256)

typedef __attribute__((ext_vector_type(4))) float f32x4;
typedef __attribute__((ext_vector_type(8))) short bf16x8;

__device__ inline unsigned short f2bf(float f) {
    unsigned u = __float_as_uint(f);
    return (unsigned short)((u + 0x7FFFu + ((u >> 16) & 1u)) >> 16);
}

// ---------------- CSR build ----------------

__global__ void k_hist(const int* __restrict__ dst, int* __restrict__ counts) {
    int e = blockIdx.x * blockDim.x + threadIdx.x;
    if (e < N_EDGES) atomicAdd(&counts[dst[e]], 1);
}

// 3-kernel scan: per-block sums -> 1-wave scan of 79 partials -> apply
__global__ void k_scan1(const int* __restrict__ counts, int* __restrict__ bsum) {
    int t = threadIdx.x, b = blockIdx.x;
    int i = b * 256 + t;
    int v = (i < N_NODES) ? counts[i] : 0;
    int s = v;
    #pragma unroll
    for (int d = 1; d < 64; d <<= 1) s += __shfl_xor(s, d, 64);
    __shared__ int ws[4];
    if ((t & 63) == 0) ws[t >> 6] = s;
    __syncthreads();
    if (t == 0) bsum[b] = ws[0] + ws[1] + ws[2] + ws[3];
}

__global__ void k_scan2(const int* __restrict__ bsum, int* __restrict__ bbase,
                        int* __restrict__ offsets) {
    int lane = threadIdx.x;   // 64 threads
    int v0 = (lane < SCAN_B) ? bsum[lane] : 0;
    int v1 = (64 + lane < SCAN_B) ? bsum[64 + lane] : 0;
    int s0 = v0;
    #pragma unroll
    for (int d = 1; d < 64; d <<= 1) { int t = __shfl_up(s0, d, 64); if (lane >= d) s0 += t; }
    int tot0 = __shfl(s0, 63, 64);
    int s1 = v1;
    #pragma unroll
    for (int d = 1; d < 64; d <<= 1) { int t = __shfl_up(s1, d, 64); if (lane >= d) s1 += t; }
    int tot1 = __shfl(s1, 63, 64);
    if (lane < SCAN_B) bbase[lane] = s0 - v0;
    if (64 + lane < SCAN_B) bbase[64 + lane] = tot0 + s1 - v1;
    if (lane == 0) offsets[N_NODES] = tot0 + tot1;
}

__global__ void k_scan3(const int* __restrict__ counts, const int* __restrict__ bbase,
                        int* __restrict__ offsets, int* __restrict__ cursor) {
    int t = threadIdx.x, b = blockIdx.x;
    int lane = t & 63, wid = t >> 6;
    int i = b * 256 + t;
    int v = (i < N_NODES) ? counts[i] : 0;
    int s = v;
    #pragma unroll
    for (int d = 1; d < 64; d <<= 1) { int u = __shfl_up(s, d, 64); if (lane >= d) s += u; }
    __shared__ int ws[4];
    if (lane == 63) ws[wid] = s;
    __syncthreads();
    int wb = 0;
    #pragma unroll
    for (int w = 0; w < 3; ++w) if (w < wid) wb += ws[w];
    int excl = bbase[b] + wb + (s - v);
    if (i < N_NODES) { offsets[i] = excl; cursor[i] = excl; }
}

__global__ void k_scatter(const int* __restrict__ src, const int* __restrict__ dst,
                          int* __restrict__ cursor, int* __restrict__ ssrc) {
    int e = blockIdx.x * blockDim.x + threadIdx.x;
    if (e < N_EDGES) {
        int d = dst[e];
        int p = atomicAdd(&cursor[d], 1);
        ssrc[p] = src[e];
    }
}

// ---------------- Wt = W_ae^T in bf16, K padded to 2048 ----------------

__global__ void k_wt(const float* __restrict__ W, unsigned short* __restrict__ Wt) {
    int idx = blockIdx.x * 256 + threadIdx.x;
    int n = idx >> 11;
    int k = idx & 2047;
    float v = (k < IN_F) ? W[(size_t)k * C_OUT + n] : 0.f;
    Wt[(size_t)n * KPAD + k] = f2bf(v);
}

// ---------------- h = x @ W_ae + b_ae  (bf16 MFMA) ----------------

__global__ __launch_bounds__(256) void k_gemm_h(
    const float* __restrict__ x, const unsigned short* __restrict__ Wt,
    const float* __restrict__ b, float* __restrict__ h) {
    __shared__ unsigned short Asw[32 * 64];
    __shared__ unsigned short Bsw[64 * 64];
    int t = threadIdx.x;
    int lane = t & 63, wid = t >> 6;
    int wr = wid >> 1, wc = wid & 1;
    int row0 = blockIdx.x * 32;

    int a_row = t & 31, a_half = t >> 5;
    int b_n = t >> 2, b_kq = t & 3;

    int rA = wr * 16 + (lane & 15);
    int kchunk = lane >> 4;
    f32x4 acc0 = {0.f, 0.f, 0.f, 0.f}, acc1 = {0.f, 0.f, 0.f, 0.f};

    for (int k0 = 0; k0 < KPAD; k0 += 64) {
        {
            uint4 wv = {0u, 0u, 0u, 0u};
            int kbase = k0 + a_half * 8;
            if (kbase < IN_F) {
                const float* src = &x[(size_t)(row0 + a_row) * IN_F + kbase];
                float4 f0 = *(const float4*)src;
                float4 f1 = *(const float4*)(src + 4);
                wv.x = (unsigned)f2bf(f0.x) | ((unsigned)f2bf(f0.y) << 16);
                wv.y = (unsigned)f2bf(f0.z) | ((unsigned)f2bf(f0.w) << 16);
                wv.z = (unsigned)f2bf(f1.x) | ((unsigned)f2bf(f1.y) << 16);
                wv.w = (unsigned)f2bf(f1.z) | ((unsigned)f2bf(f1.w) << 16);
            }
            int slot = a_half ^ (a_row & 7);
            *(uint4*)((char*)Asw + a_row * 128 + slot * 16) = wv;
        }
        {
            const uint4* src = (const uint4*)&Wt[(size_t)b_n * KPAD + k0 + b_kq * 16];
            uint4 w0 = src[0], w1 = src[1];
            int s0 = (b_kq * 2) ^ (b_n & 7);
            int s1 = (b_kq * 2 + 1) ^ (b_n & 7);
            *(uint4*)((char*)Bsw + b_n * 128 + s0 * 16) = w0;
            *(uint4*)((char*)Bsw + b_n * 128 + s1 * 16) = w1;
        }
        __syncthreads();
        #pragma unroll
        for (int ks = 0; ks < 2; ++ks) {
            int aslot = (ks * 4 + kchunk) ^ (rA & 7);
            bf16x8 af = *(bf16x8*)((char*)Asw + rA * 128 + aslot * 16);
            {
                int cb = wc * 32 + (lane & 15);
                int bslot = (ks * 4 + kchunk) ^ (cb & 7);
                bf16x8 bfr = *(bf16x8*)((char*)Bsw + cb * 128 + bslot * 16);
                acc0 = __builtin_amdgcn_mfma_f32_16x16x32_bf16(af, bfr, acc0, 0, 0, 0);
            }
            {
                int cb = wc * 32 + 16 + (lane & 15);
                int bslot = (ks * 4 + kchunk) ^ (cb & 7);
                bf16x8 bfr = *(bf16x8*)((char*)Bsw + cb * 128 + bslot * 16);
                acc1 = __builtin_amdgcn_mfma_f32_16x16x32_bf16(af, bfr, acc1, 0, 0, 0);
            }
        }
        __syncthreads();
    }
    int ci = (lane >> 4) * 4;
    int cj = lane & 15;
    #pragma unroll
    for (int nt = 0; nt < 2; ++nt) {
        f32x4 a = nt ? acc1 : acc0;
        int col = wc * 32 + nt * 16 + cj;
        float bb = b[col];
        #pragma unroll
        for (int r = 0; r < 4; ++r) {
            int grow = row0 + wr * 16 + ci + r;
            h[(size_t)grow * C_OUT + col] = a[r] + bb;
        }
    }
}

// ---------------- xl (bf16) | xr (fp32) = h @ [Wl|Wr] + [bl|br] ----------------

__global__ __launch_bounds__(256) void k_xlxr2(
    const float* __restrict__ h, const float* __restrict__ Wl, const float* __restrict__ bl,
    const float* __restrict__ Wr, const float* __restrict__ br,
    unsigned short* __restrict__ xlb, float* __restrict__ xr) {
    __shared__ float hs[64][68];
    __shared__ float Ws[64][128];
    int t = threadIdx.x;
    int mb = blockIdx.x >> 2, nb = blockIdx.x & 3;
    int node0 = mb * 64;
    const float* Wsrc = (nb < 2) ? (Wl + nb * 128) : (Wr + (nb - 2) * 128);
    const float* bsrc = (nb < 2) ? (bl + nb * 128) : (br + (nb - 2) * 128);

    {
        int row = t >> 2, q = t & 3;
        int gnode = node0 + row; if (gnode >= N_NODES) gnode = N_NODES - 1;
        const float4* src = (const float4*)&h[(size_t)gnode * C_OUT + q * 16];
        *(float4*)&hs[row][q * 16 + 0]  = src[0];
        *(float4*)&hs[row][q * 16 + 4]  = src[1];
        *(float4*)&hs[row][q * 16 + 8]  = src[2];
        *(float4*)&hs[row][q * 16 + 12] = src[3];
    }
    {
        #pragma unroll
        for (int i = 0; i < 8; ++i) {
            int f = t + i * 256;
            int k = f >> 5, c4 = (f & 31) << 2;
            *(float4*)&Ws[k][c4] = *(const float4*)&Wsrc[(size_t)k * HC + c4];
        }
    }
    __syncthreads();

    int tr = t >> 5;
    int tc = t & 31;
    float4 acc[8];
    float4 bv = *(const float4*)&bsrc[tc * 4];
    #pragma unroll
    for (int r = 0; r < 8; ++r) acc[r] = bv;

    for (int k4 = 0; k4 < 64; k4 += 4) {
        float4 w0 = *(float4*)&Ws[k4 + 0][tc * 4];
        float4 w1 = *(float4*)&Ws[k4 + 1][tc * 4];
        float4 w2 = *(float4*)&Ws[k4 + 2][tc * 4];
        float4 w3 = *(float4*)&Ws[k4 + 3][tc * 4];
        #pragma unroll
        for (int r = 0; r < 8; ++r) {
            float4 a = *(float4*)&hs[tr * 8 + r][k4];
            acc[r].x += a.x * w0.x + a.y * w1.x + a.z * w2.x + a.w * w3.x;
            acc[r].y += a.x * w0.y + a.y * w1.y + a.z * w2.y + a.w * w3.y;
            acc[r].z += a.x * w0.z + a.y * w1.z + a.z * w2.z + a.w * w3.z;
            acc[r].w += a.x * w0.w + a.y * w1.w + a.z * w2.w + a.w * w3.w;
        }
    }
    #pragma unroll
    for (int r = 0; r < 8; ++r) {
        int gnode = node0 + tr * 8 + r;
        if (gnode < N_NODES) {
            if (nb < 2) {
                ushort4 o;
                o.x = f2bf(acc[r].x); o.y = f2bf(acc[r].y);
                o.z = f2bf(acc[r].z); o.w = f2bf(acc[r].w);
                *(ushort4*)&xlb[(size_t)gnode * HC + nb * 128 + tc * 4] = o;
            } else {
                *(float4*)&xr[(size_t)gnode * HC + (nb - 2) * 128 + tc * 4] = acc[r];
            }
        }
    }
}

// ---------------- fused attention + linear + residual + LayerNorm ----------------
// 4 edges/wave: sub = lane>>4 picks the edge, sl = lane&15 -> channels sl*16..+15.
// head(channel-group sl) = sl>>2; per-head logit reduce = shfl_xor 1,2 (4 lanes);
// cross-slot (edge) reduce = shfl_xor 16,32 once per node.

__global__ __launch_bounds__(256) void k_attn(
    const unsigned short* __restrict__ xlb, const float* __restrict__ xr,
    const float* __restrict__ h, const int* __restrict__ offsets,
    const int* __restrict__ ssrc, const float* __restrict__ att,
    const float* __restrict__ b_conv, const float* __restrict__ W_lin,
    const float* __restrict__ b_lin, const float* __restrict__ ln_w,
    const float* __restrict__ ln_b, float* __restrict__ out) {
    __shared__ float sh[4][HC];
    int wid = threadIdx.x >> 6, lane = threadIdx.x & 63;
    int node = blockIdx.x * 4 + wid;
    int sub = lane >> 4;     // edge slot 0..3
    int sl  = lane & 15;     // channel group
    int c0  = sl * 16;

    float xri[16], attv[16];
    #pragma unroll
    for (int i = 0; i < 4; ++i) {
        float4 t4 = *(const float4*)&xr[(size_t)node * HC + c0 + i * 4];
        xri[i*4+0] = t4.x; xri[i*4+1] = t4.y; xri[i*4+2] = t4.z; xri[i*4+3] = t4.w;
        float4 a4 = *(const float4*)&att[c0 + i * 4];
        attv[i*4+0] = a4.x; attv[i*4+1] = a4.y; attv[i*4+2] = a4.z; attv[i*4+3] = a4.w;
    }
    float acc[16];
    #pragma unroll
    for (int i = 0; i < 16; ++i) acc[i] = 0.f;
    float denom = 0.f;

    auto edge_do = [&](int j, bool valid) {
        const uint4* rp = (const uint4*)&xlb[(size_t)j * HC + c0];
        uint4 w0 = rp[0], w1 = rp[1];
        float xlj[16];
        xlj[0]  = __uint_as_float(w0.x << 16); xlj[1]  = __uint_as_float(w0.x & 0xFFFF0000u);
        xlj[2]  = __uint_as_float(w0.y << 16); xlj[3]  = __uint_as_float(w0.y & 0xFFFF0000u);
        xlj[4]  = __uint_as_float(w0.z << 16); xlj[5]  = __uint_as_float(w0.z & 0xFFFF0000u);
        xlj[6]  = __uint_as_float(w0.w << 16); xlj[7]  = __uint_as_float(w0.w & 0xFFFF0000u);
        xlj[8]  = __uint_as_float(w1.x << 16); xlj[9]  = __uint_as_float(w1.x & 0xFFFF0000u);
        xlj[10] = __uint_as_float(w1.y << 16); xlj[11] = __uint_as_float(w1.y & 0xFFFF0000u);
        xlj[12] = __uint_as_float(w1.z << 16); xlj[13] = __uint_as_float(w1.z & 0xFFFF0000u);
        xlj[14] = __uint_as_float(w1.w << 16); xlj[15] = __uint_as_float(w1.w & 0xFFFF0000u);
        float p = 0.f;
        #pragma unroll
        for (int i = 0; i < 16; ++i) {
            float g = xlj[i] + xri[i];
            g = fmaxf(g, 0.f) + NEG * fminf(g, 0.f);
            p += g * attv[i];
        }
        p += __shfl_xor(p, 1); p += __shfl_xor(p, 2);   // 4-lane = one head
        float ex = valid ? __expf(p) : 0.f;             // logits O(1): no max shift
        denom += ex;
        #pragma unroll
        for (int i = 0; i < 16; ++i) acc[i] += ex * xlj[i];
    };

    edge_do(node, sub == 0);   // self loop counted once
    int s0 = offsets[node], s1 = offsets[node + 1];
    for (int base = s0; base < s1; base += 64) {
        int rem = s1 - base;
        int cnt = rem < 64 ? rem : 64;
        int jv = (base + lane < s1) ? ssrc[base + lane] : 0;
        int niter = (cnt + 3) >> 2;
        for (int it = 0; it < niter; ++it) {
            int ei = (it << 2) + sub;
            int j = __shfl(jv, ei, 64);
            edge_do(j, ei < cnt);
        }
    }

    // reduce over the 4 edge slots
    #pragma unroll
    for (int i = 0; i < 16; ++i) {
        acc[i] += __shfl_xor(acc[i], 16);
        acc[i] += __shfl_xor(acc[i], 32);
    }
    denom += __shfl_xor(denom, 16);
    denom += __shfl_xor(denom, 32);

    float inv = 1.f / denom;
    if (sub == 0) {
        #pragma unroll
        for (int i = 0; i < 4; ++i) {
            float4 bc = *(const float4*)&b_conv[c0 + i * 4];
            float4 o = { acc[i*4+0] * inv + bc.x, acc[i*4+1] * inv + bc.y,
                         acc[i*4+2] * inv + bc.z, acc[i*4+3] * inv + bc.w };
            *(float4*)&sh[wid][c0 + i * 4] = o;
        }
    }
    __syncthreads();

    // a = relu(ov @ W_lin + b_lin); lane = output channel
    float s = b_lin[lane];
    #pragma unroll 8
    for (int k = 0; k < HC; k += 4) {
        float4 o4 = *(float4*)&sh[wid][k];
        s += o4.x * W_lin[(k + 0) * C_OUT + lane];
        s += o4.y * W_lin[(k + 1) * C_OUT + lane];
        s += o4.z * W_lin[(k + 2) * C_OUT + lane];
        s += o4.w * W_lin[(k + 3) * C_OUT + lane];
    }
    float a = s > 0.f ? s : 0.f;
    float y = a + h[(size_t)node * C_OUT + lane];

    float m = y;
    m += __shfl_xor(m, 1);  m += __shfl_xor(m, 2);  m += __shfl_xor(m, 4);
    m += __shfl_xor(m, 8);  m += __shfl_xor(m, 16); m += __shfl_xor(m, 32);
    m *= (1.f / 64.f);
    float d = y - m;
    float v2 = d * d;
    v2 += __shfl_xor(v2, 1);  v2 += __shfl_xor(v2, 2);  v2 += __shfl_xor(v2, 4);
    v2 += __shfl_xor(v2, 8);  v2 += __shfl_xor(v2, 16); v2 += __shfl_xor(v2, 32);
    v2 *= (1.f / 64.f);
    out[(size_t)node * C_OUT + lane] = ln_w[lane] * d * rsqrtf(v2 + 1e-12f) + ln_b[lane];
}

// ---------------- launch ----------------

extern "C" void kernel_launch(void* const* d_in, const int* in_sizes, int n_in,
                              void* d_out, int out_size, void* d_ws, size_t ws_size,
                              hipStream_t stream) {
    const float* x     = (const float*)d_in[0];
    const int*   ei    = (const int*)  d_in[1];
    const float* W_ae  = (const float*)d_in[2];
    const float* b_ae  = (const float*)d_in[3];
    const float* Wl    = (const float*)d_in[4];
    const float* bl    = (const float*)d_in[5];
    const float* Wr    = (const float*)d_in[6];
    const float* br    = (const float*)d_in[7];
    const float* att   = (const float*)d_in[8];
    const float* b_conv= (const float*)d_in[9];
    const float* W_lin = (const float*)d_in[10];
    const float* b_lin = (const float*)d_in[11];
    const float* ln_w  = (const float*)d_in[12];
    const float* ln_b  = (const float*)d_in[13];
    float* out = (float*)d_out;
    const int* src = ei;
    const int* dst = ei + N_EDGES;

    char* ws = (char*)d_ws;
    size_t off = 0;
    auto alloc = [&](size_t bytes) {
        void* p = ws + off;
        off = (off + bytes + 255) & ~(size_t)255;
        return p;
    };
    float* h       = (float*)alloc((size_t)N_NODES * C_OUT * 4);
    unsigned short* xlb = (unsigned short*)alloc((size_t)N_NODES * HC * 2);
    float* xr      = (float*)alloc((size_t)N_NODES * HC * 4);
    int*   counts  = (int*)  alloc((size_t)N_NODES * 4);
    int*   offsets = (int*)  alloc((size_t)(N_NODES + 1) * 4);
    int*   cursor  = (int*)  alloc((size_t)N_NODES * 4);
    int*   ssrc    = (int*)  alloc((size_t)N_EDGES * 4);
    unsigned short* Wt = (unsigned short*)alloc((size_t)C_OUT * KPAD * 2);
    int*   bsum    = (int*)  alloc((size_t)SCAN_B * 4);
    int*   bbase   = (int*)  alloc((size_t)SCAN_B * 4);

    hipMemsetAsync(counts, 0, (size_t)N_NODES * 4, stream);
    k_hist   <<<(N_EDGES + 255) / 256, 256, 0, stream>>>(dst, counts);
    k_scan1  <<<SCAN_B, 256, 0, stream>>>(counts, bsum);
    k_scan2  <<<1, 64, 0, stream>>>(bsum, bbase, offsets);
    k_scan3  <<<SCAN_B, 256, 0, stream>>>(counts, bbase, offsets, cursor);
    k_scatter<<<(N_EDGES + 255) / 256, 256, 0, stream>>>(src, dst, cursor, ssrc);
    k_wt     <<<(C_OUT * KPAD) / 256, 256, 0, stream>>>(W_ae, Wt);
    k_gemm_h <<<N_NODES / 32, 256, 0, stream>>>(x, Wt, b_ae, h);
    k_xlxr2  <<<((N_NODES + 63) / 64) * 4, 256, 0, stream>>>(h, Wl, bl, Wr, br, xlb, xr);
    k_attn   <<<N_NODES / 4, 256, 0, stream>>>(xlb, xr, h, offsets, ssrc, att,
                                               b_conv, W_lin, b_lin, ln_w, ln_b, out);
}

// Round 9
// 217.356 us; speedup vs baseline: 1.9158x; 1.0505x over previous
//
#include <hip/hip_runtime.h>
#include <hip/hip_fp16.h>

#define N_NODES 20000
#define N_EDGES 640000
#define IN_F    2000
#define KPAD    2048
#define C_OUT   64
#define HC      256   // HEADS * C_OUT
#define NEG     0.2f
#define SCAN_B  79    // ceil(20000/256)

typedef __attribute__((ext_vector_type(4))) float f32x4;
typedef __attribute__((ext_vector_type(8))) short bf16x8;
typedef _Float16 h2 __attribute__((ext_vector_type(2)));   // packed fp16 pair

__device__ inline unsigned short f2bf(float f) {
    unsigned u = __float_as_uint(f);
    return (unsigned short)((u + 0x7FFFu + ((u >> 16) & 1u)) >> 16);
}

// ---------------- CSR build ----------------

__global__ void k_hist(const int* __restrict__ dst, int* __restrict__ counts) {
    int e = blockIdx.x * blockDim.x + threadIdx.x;
    if (e < N_EDGES) atomicAdd(&counts[dst[e]], 1);
}

__global__ void k_scan1(const int* __restrict__ counts, int* __restrict__ bsum) {
    int t = threadIdx.x, b = blockIdx.x;
    int i = b * 256 + t;
    int v = (i < N_NODES) ? counts[i] : 0;
    int s = v;
    #pragma unroll
    for (int d = 1; d < 64; d <<= 1) s += __shfl_xor(s, d, 64);
    __shared__ int ws[4];
    if ((t & 63) == 0) ws[t >> 6] = s;
    __syncthreads();
    if (t == 0) bsum[b] = ws[0] + ws[1] + ws[2] + ws[3];
}

__global__ void k_scan2(const int* __restrict__ bsum, int* __restrict__ bbase,
                        int* __restrict__ offsets) {
    int lane = threadIdx.x;   // 64 threads
    int v0 = (lane < SCAN_B) ? bsum[lane] : 0;
    int v1 = (64 + lane < SCAN_B) ? bsum[64 + lane] : 0;
    int s0 = v0;
    #pragma unroll
    for (int d = 1; d < 64; d <<= 1) { int t = __shfl_up(s0, d, 64); if (lane >= d) s0 += t; }
    int tot0 = __shfl(s0, 63, 64);
    int s1 = v1;
    #pragma unroll
    for (int d = 1; d < 64; d <<= 1) { int t = __shfl_up(s1, d, 64); if (lane >= d) s1 += t; }
    int tot1 = __shfl(s1, 63, 64);
    if (lane < SCAN_B) bbase[lane] = s0 - v0;
    if (64 + lane < SCAN_B) bbase[64 + lane] = tot0 + s1 - v1;
    if (lane == 0) offsets[N_NODES] = tot0 + tot1;
}

__global__ void k_scan3(const int* __restrict__ counts, const int* __restrict__ bbase,
                        int* __restrict__ offsets, int* __restrict__ cursor) {
    int t = threadIdx.x, b = blockIdx.x;
    int lane = t & 63, wid = t >> 6;
    int i = b * 256 + t;
    int v = (i < N_NODES) ? counts[i] : 0;
    int s = v;
    #pragma unroll
    for (int d = 1; d < 64; d <<= 1) { int u = __shfl_up(s, d, 64); if (lane >= d) s += u; }
    __shared__ int ws[4];
    if (lane == 63) ws[wid] = s;
    __syncthreads();
    int wb = 0;
    #pragma unroll
    for (int w = 0; w < 3; ++w) if (w < wid) wb += ws[w];
    int excl = bbase[b] + wb + (s - v);
    if (i < N_NODES) { offsets[i] = excl; cursor[i] = excl; }
}

__global__ void k_scatter(const int* __restrict__ src, const int* __restrict__ dst,
                          int* __restrict__ cursor, int* __restrict__ ssrc) {
    int e = blockIdx.x * blockDim.x + threadIdx.x;
    if (e < N_EDGES) {
        int d = dst[e];
        int p = atomicAdd(&cursor[d], 1);
        ssrc[p] = src[e];
    }
}

// ---------------- Wt = W_ae^T in bf16, K padded to 2048 ----------------

__global__ void k_wt(const float* __restrict__ W, unsigned short* __restrict__ Wt) {
    int idx = blockIdx.x * 256 + threadIdx.x;
    int n = idx >> 11;
    int k = idx & 2047;
    float v = (k < IN_F) ? W[(size_t)k * C_OUT + n] : 0.f;
    Wt[(size_t)n * KPAD + k] = f2bf(v);
}

// ---------------- h = x @ W_ae + b_ae  (bf16 MFMA) ----------------

__global__ __launch_bounds__(256) void k_gemm_h(
    const float* __restrict__ x, const unsigned short* __restrict__ Wt,
    const float* __restrict__ b, float* __restrict__ h) {
    __shared__ unsigned short Asw[32 * 64];
    __shared__ unsigned short Bsw[64 * 64];
    int t = threadIdx.x;
    int lane = t & 63, wid = t >> 6;
    int wr = wid >> 1, wc = wid & 1;
    int row0 = blockIdx.x * 32;

    int a_row = t & 31, a_half = t >> 5;
    int b_n = t >> 2, b_kq = t & 3;

    int rA = wr * 16 + (lane & 15);
    int kchunk = lane >> 4;
    f32x4 acc0 = {0.f, 0.f, 0.f, 0.f}, acc1 = {0.f, 0.f, 0.f, 0.f};

    for (int k0 = 0; k0 < KPAD; k0 += 64) {
        {
            uint4 wv = {0u, 0u, 0u, 0u};
            int kbase = k0 + a_half * 8;
            if (kbase < IN_F) {
                const float* src = &x[(size_t)(row0 + a_row) * IN_F + kbase];
                float4 f0 = *(const float4*)src;
                float4 f1 = *(const float4*)(src + 4);
                wv.x = (unsigned)f2bf(f0.x) | ((unsigned)f2bf(f0.y) << 16);
                wv.y = (unsigned)f2bf(f0.z) | ((unsigned)f2bf(f0.w) << 16);
                wv.z = (unsigned)f2bf(f1.x) | ((unsigned)f2bf(f1.y) << 16);
                wv.w = (unsigned)f2bf(f1.z) | ((unsigned)f2bf(f1.w) << 16);
            }
            int slot = a_half ^ (a_row & 7);
            *(uint4*)((char*)Asw + a_row * 128 + slot * 16) = wv;
        }
        {
            const uint4* src = (const uint4*)&Wt[(size_t)b_n * KPAD + k0 + b_kq * 16];
            uint4 w0 = src[0], w1 = src[1];
            int s0 = (b_kq * 2) ^ (b_n & 7);
            int s1 = (b_kq * 2 + 1) ^ (b_n & 7);
            *(uint4*)((char*)Bsw + b_n * 128 + s0 * 16) = w0;
            *(uint4*)((char*)Bsw + b_n * 128 + s1 * 16) = w1;
        }
        __syncthreads();
        #pragma unroll
        for (int ks = 0; ks < 2; ++ks) {
            int aslot = (ks * 4 + kchunk) ^ (rA & 7);
            bf16x8 af = *(bf16x8*)((char*)Asw + rA * 128 + aslot * 16);
            {
                int cb = wc * 32 + (lane & 15);
                int bslot = (ks * 4 + kchunk) ^ (cb & 7);
                bf16x8 bfr = *(bf16x8*)((char*)Bsw + cb * 128 + bslot * 16);
                acc0 = __builtin_amdgcn_mfma_f32_16x16x32_bf16(af, bfr, acc0, 0, 0, 0);
            }
            {
                int cb = wc * 32 + 16 + (lane & 15);
                int bslot = (ks * 4 + kchunk) ^ (cb & 7);
                bf16x8 bfr = *(bf16x8*)((char*)Bsw + cb * 128 + bslot * 16);
                acc1 = __builtin_amdgcn_mfma_f32_16x16x32_bf16(af, bfr, acc1, 0, 0, 0);
            }
        }
        __syncthreads();
    }
    int ci = (lane >> 4) * 4;
    int cj = lane & 15;
    #pragma unroll
    for (int nt = 0; nt < 2; ++nt) {
        f32x4 a = nt ? acc1 : acc0;
        int col = wc * 32 + nt * 16 + cj;
        float bb = b[col];
        #pragma unroll
        for (int r = 0; r < 4; ++r) {
            int grow = row0 + wr * 16 + ci + r;
            h[(size_t)grow * C_OUT + col] = a[r] + bb;
        }
    }
}

// ---------------- xl (fp16) | xr (fp32) = h @ [Wl|Wr] + [bl|br] ----------------

__global__ __launch_bounds__(256) void k_xlxr2(
    const float* __restrict__ h, const float* __restrict__ Wl, const float* __restrict__ bl,
    const float* __restrict__ Wr, const float* __restrict__ br,
    unsigned short* __restrict__ xlh, float* __restrict__ xr) {
    __shared__ float hs[64][68];
    __shared__ float Ws[64][128];
    int t = threadIdx.x;
    int mb = blockIdx.x >> 2, nb = blockIdx.x & 3;
    int node0 = mb * 64;
    const float* Wsrc = (nb < 2) ? (Wl + nb * 128) : (Wr + (nb - 2) * 128);
    const float* bsrc = (nb < 2) ? (bl + nb * 128) : (br + (nb - 2) * 128);

    {
        int row = t >> 2, q = t & 3;
        int gnode = node0 + row; if (gnode >= N_NODES) gnode = N_NODES - 1;
        const float4* src = (const float4*)&h[(size_t)gnode * C_OUT + q * 16];
        *(float4*)&hs[row][q * 16 + 0]  = src[0];
        *(float4*)&hs[row][q * 16 + 4]  = src[1];
        *(float4*)&hs[row][q * 16 + 8]  = src[2];
        *(float4*)&hs[row][q * 16 + 12] = src[3];
    }
    {
        #pragma unroll
        for (int i = 0; i < 8; ++i) {
            int f = t + i * 256;
            int k = f >> 5, c4 = (f & 31) << 2;
            *(float4*)&Ws[k][c4] = *(const float4*)&Wsrc[(size_t)k * HC + c4];
        }
    }
    __syncthreads();

    int tr = t >> 5;
    int tc = t & 31;
    float4 acc[8];
    float4 bv = *(const float4*)&bsrc[tc * 4];
    #pragma unroll
    for (int r = 0; r < 8; ++r) acc[r] = bv;

    for (int k4 = 0; k4 < 64; k4 += 4) {
        float4 w0 = *(float4*)&Ws[k4 + 0][tc * 4];
        float4 w1 = *(float4*)&Ws[k4 + 1][tc * 4];
        float4 w2 = *(float4*)&Ws[k4 + 2][tc * 4];
        float4 w3 = *(float4*)&Ws[k4 + 3][tc * 4];
        #pragma unroll
        for (int r = 0; r < 8; ++r) {
            float4 a = *(float4*)&hs[tr * 8 + r][k4];
            acc[r].x += a.x * w0.x + a.y * w1.x + a.z * w2.x + a.w * w3.x;
            acc[r].y += a.x * w0.y + a.y * w1.y + a.z * w2.y + a.w * w3.y;
            acc[r].z += a.x * w0.z + a.y * w1.z + a.z * w2.z + a.w * w3.z;
            acc[r].w += a.x * w0.w + a.y * w1.w + a.z * w2.w + a.w * w3.w;
        }
    }
    #pragma unroll
    for (int r = 0; r < 8; ++r) {
        int gnode = node0 + tr * 8 + r;
        if (gnode < N_NODES) {
            if (nb < 2) {
                h2 lo = { (_Float16)acc[r].x, (_Float16)acc[r].y };
                h2 hi = { (_Float16)acc[r].z, (_Float16)acc[r].w };
                uint2 o = { __builtin_bit_cast(unsigned, lo),
                            __builtin_bit_cast(unsigned, hi) };
                *(uint2*)&xlh[(size_t)gnode * HC + nb * 128 + tc * 4] = o;
            } else {
                *(float4*)&xr[(size_t)gnode * HC + (nb - 2) * 128 + tc * 4] = acc[r];
            }
        }
    }
}

// ---------------- fused attention + linear + residual + LayerNorm ----------------
// 4 edges/wave (sub = lane>>4); lane covers 16 channels (sl*16..) as 8 fp16 pairs.
// Packed fp16 (v_pk_*) for leaky+dot+accumulate; fp32 for exp/denom/reductions.

__global__ __launch_bounds__(256) void k_attn(
    const unsigned short* __restrict__ xlh, const float* __restrict__ xr,
    const float* __restrict__ h, const int* __restrict__ offsets,
    const int* __restrict__ ssrc, const float* __restrict__ att,
    const float* __restrict__ b_conv, const float* __restrict__ W_lin,
    const float* __restrict__ b_lin, const float* __restrict__ ln_w,
    const float* __restrict__ ln_b, float* __restrict__ out) {
    __shared__ float sh[4][HC];
    int wid = threadIdx.x >> 6, lane = threadIdx.x & 63;
    int node = blockIdx.x * 4 + wid;
    int sub = lane >> 4;     // edge slot 0..3
    int sl  = lane & 15;     // channel group
    int c0  = sl * 16;

    const h2 z2  = { (_Float16)0.f, (_Float16)0.f };
    const h2 ns2 = { (_Float16)NEG, (_Float16)NEG };

    h2 xr2[8], at2[8];
    #pragma unroll
    for (int i = 0; i < 4; ++i) {
        float4 t4 = *(const float4*)&xr[(size_t)node * HC + c0 + i * 4];
        xr2[i*2+0] = h2{ (_Float16)t4.x, (_Float16)t4.y };
        xr2[i*2+1] = h2{ (_Float16)t4.z, (_Float16)t4.w };
        float4 a4 = *(const float4*)&att[c0 + i * 4];
        at2[i*2+0] = h2{ (_Float16)a4.x, (_Float16)a4.y };
        at2[i*2+1] = h2{ (_Float16)a4.z, (_Float16)a4.w };
    }
    h2 acc2[8];
    #pragma unroll
    for (int i = 0; i < 8; ++i) acc2[i] = z2;
    float denom = 0.f;

    auto edge_do = [&](int j, bool valid) {
        const uint4* rp = (const uint4*)&xlh[(size_t)j * HC + c0];
        uint4 w0 = rp[0], w1 = rp[1];
        h2 x2[8];
        x2[0] = __builtin_bit_cast(h2, w0.x); x2[1] = __builtin_bit_cast(h2, w0.y);
        x2[2] = __builtin_bit_cast(h2, w0.z); x2[3] = __builtin_bit_cast(h2, w0.w);
        x2[4] = __builtin_bit_cast(h2, w1.x); x2[5] = __builtin_bit_cast(h2, w1.y);
        x2[6] = __builtin_bit_cast(h2, w1.z); x2[7] = __builtin_bit_cast(h2, w1.w);
        h2 p2 = z2;
        #pragma unroll
        for (int i = 0; i < 8; ++i) {
            h2 g   = x2[i] + xr2[i];
            h2 pos = __builtin_elementwise_max(g, z2);
            h2 neg = __builtin_elementwise_min(g, z2);
            g = pos + neg * ns2;
            p2 += g * at2[i];
        }
        float p = (float)p2.x + (float)p2.y;
        p += __shfl_xor(p, 1); p += __shfl_xor(p, 2);   // 4 lanes = one head
        float ex = valid ? __expf(p) : 0.f;             // logits O(1): no max shift
        denom += ex;
        h2 e2 = { (_Float16)ex, (_Float16)ex };
        #pragma unroll
        for (int i = 0; i < 8; ++i) acc2[i] += e2 * x2[i];
    };

    edge_do(node, sub == 0);   // self loop counted once
    int s0 = offsets[node], s1 = offsets[node + 1];
    for (int base = s0; base < s1; base += 64) {
        int rem = s1 - base;
        int cnt = rem < 64 ? rem : 64;
        int jv = (base + lane < s1) ? ssrc[base + lane] : 0;
        int niter = (cnt + 3) >> 2;
        for (int it = 0; it < niter; ++it) {
            int ei = (it << 2) + sub;
            int j = __shfl(jv, ei, 64);
            edge_do(j, ei < cnt);
        }
    }

    // unpack to fp32, reduce over the 4 edge slots
    float accf[16];
    #pragma unroll
    for (int i = 0; i < 8; ++i) {
        accf[2*i]   = (float)acc2[i].x;
        accf[2*i+1] = (float)acc2[i].y;
    }
    #pragma unroll
    for (int i = 0; i < 16; ++i) {
        accf[i] += __shfl_xor(accf[i], 16);
        accf[i] += __shfl_xor(accf[i], 32);
    }
    denom += __shfl_xor(denom, 16);
    denom += __shfl_xor(denom, 32);

    float inv = 1.f / denom;
    if (sub == 0) {
        #pragma unroll
        for (int i = 0; i < 4; ++i) {
            float4 bc = *(const float4*)&b_conv[c0 + i * 4];
            float4 o = { accf[i*4+0] * inv + bc.x, accf[i*4+1] * inv + bc.y,
                         accf[i*4+2] * inv + bc.z, accf[i*4+3] * inv + bc.w };
            *(float4*)&sh[wid][c0 + i * 4] = o;
        }
    }
    __syncthreads();

    // a = relu(ov @ W_lin + b_lin); lane = output channel
    float s = b_lin[lane];
    #pragma unroll 8
    for (int k = 0; k < HC; k += 4) {
        float4 o4 = *(float4*)&sh[wid][k];
        s += o4.x * W_lin[(k + 0) * C_OUT + lane];
        s += o4.y * W_lin[(k + 1) * C_OUT + lane];
        s += o4.z * W_lin[(k + 2) * C_OUT + lane];
        s += o4.w * W_lin[(k + 3) * C_OUT + lane];
    }
    float a = s > 0.f ? s : 0.f;
    float y = a + h[(size_t)node * C_OUT + lane];

    float m = y;
    m += __shfl_xor(m, 1);  m += __shfl_xor(m, 2);  m += __shfl_xor(m, 4);
    m += __shfl_xor(m, 8);  m += __shfl_xor(m, 16); m += __shfl_xor(m, 32);
    m *= (1.f / 64.f);
    float d = y - m;
    float v2 = d * d;
    v2 += __shfl_xor(v2, 1);  v2 += __shfl_xor(v2, 2);  v2 += __shfl_xor(v2, 4);
    v2 += __shfl_xor(v2, 8);  v2 += __shfl_xor(v2, 16); v2 += __shfl_xor(v2, 32);
    v2 *= (1.f / 64.f);
    out[(size_t)node * C_OUT + lane] = ln_w[lane] * d * rsqrtf(v2 + 1e-12f) + ln_b[lane];
}

// ---------------- launch ----------------

extern "C" void kernel_launch(void* const* d_in, const int* in_sizes, int n_in,
                              void* d_out, int out_size, void* d_ws, size_t ws_size,
                              hipStream_t stream) {
    const float* x     = (const float*)d_in[0];
    const int*   ei    = (const int*)  d_in[1];
    const float* W_ae  = (const float*)d_in[2];
    const float* b_ae  = (const float*)d_in[3];
    const float* Wl    = (const float*)d_in[4];
    const float* bl    = (const float*)d_in[5];
    const float* Wr    = (const float*)d_in[6];
    const float* br    = (const float*)d_in[7];
    const float* att   = (const float*)d_in[8];
    const float* b_conv= (const float*)d_in[9];
    const float* W_lin = (const float*)d_in[10];
    const float* b_lin = (const float*)d_in[11];
    const float* ln_w  = (const float*)d_in[12];
    const float* ln_b  = (const float*)d_in[13];
    float* out = (float*)d_out;
    const int* src = ei;
    const int* dst = ei + N_EDGES;

    char* ws = (char*)d_ws;
    size_t off = 0;
    auto alloc = [&](size_t bytes) {
        void* p = ws + off;
        off = (off + bytes + 255) & ~(size_t)255;
        return p;
    };
    float* h       = (float*)alloc((size_t)N_NODES * C_OUT * 4);
    unsigned short* xlh = (unsigned short*)alloc((size_t)N_NODES * HC * 2);
    float* xr      = (float*)alloc((size_t)N_NODES * HC * 4);
    int*   counts  = (int*)  alloc((size_t)N_NODES * 4);
    int*   offsets = (int*)  alloc((size_t)(N_NODES + 1) * 4);
    int*   cursor  = (int*)  alloc((size_t)N_NODES * 4);
    int*   ssrc    = (int*)  alloc((size_t)N_EDGES * 4);
    unsigned short* Wt = (unsigned short*)alloc((size_t)C_OUT * KPAD * 2);
    int*   bsum    = (int*)  alloc((size_t)SCAN_B * 4);
    int*   bbase   = (int*)  alloc((size_t)SCAN_B * 4);

    (void)hipMemsetAsync(counts, 0, (size_t)N_NODES * 4, stream);
    k_hist   <<<(N_EDGES + 255) / 256, 256, 0, stream>>>(dst, counts);
    k_scan1  <<<SCAN_B, 256, 0, stream>>>(counts, bsum);
    k_scan2  <<<1, 64, 0, stream>>>(bsum, bbase, offsets);
    k_scan3  <<<SCAN_B, 256, 0, stream>>>(counts, bbase, offsets, cursor);
    k_scatter<<<(N_EDGES + 255) / 256, 256, 0, stream>>>(src, dst, cursor, ssrc);
    k_wt     <<<(C_OUT * KPAD) / 256, 256, 0, stream>>>(W_ae, Wt);
    k_gemm_h <<<N_NODES / 32, 256, 0, stream>>>(x, Wt, b_ae, h);
    k_xlxr2  <<<((N_NODES + 63) / 64) * 4, 256, 0, stream>>>(h, Wl, bl, Wr, br, xlh, xr);
    k_attn   <<<N_NODES / 4, 256, 0, stream>>>(xlh, xr, h, offsets, ssrc, att,
                                               b_conv, W_lin, b_lin, ln_w, ln_b, out);
}

// Round 10
// 213.754 us; speedup vs baseline: 1.9481x; 1.0169x over previous
//
#include <hip/hip_runtime.h>
#include <hip/hip_fp16.h>

#define N_NODES 20000
#define N_EDGES 640000
#define IN_F    2000
#define KPAD    2048
#define C_OUT   64
#define HC      256   // HEADS * C_OUT
#define NEG     0.2f
#define SCAN_B  79    // ceil(20000/256)

typedef __attribute__((ext_vector_type(4))) float f32x4;
typedef __attribute__((ext_vector_type(8))) short bf16x8;
typedef _Float16 h2 __attribute__((ext_vector_type(2)));   // packed fp16 pair

__device__ inline unsigned short f2bf(float f) {
    unsigned u = __float_as_uint(f);
    return (unsigned short)((u + 0x7FFFu + ((u >> 16) & 1u)) >> 16);
}

// ---------------- CSR build ----------------

__global__ void k_hist(const int* __restrict__ dst, int* __restrict__ counts) {
    int e = blockIdx.x * blockDim.x + threadIdx.x;
    if (e < N_EDGES) atomicAdd(&counts[dst[e]], 1);
}

__global__ void k_scan1(const int* __restrict__ counts, int* __restrict__ bsum) {
    int t = threadIdx.x, b = blockIdx.x;
    int i = b * 256 + t;
    int v = (i < N_NODES) ? counts[i] : 0;
    int s = v;
    #pragma unroll
    for (int d = 1; d < 64; d <<= 1) s += __shfl_xor(s, d, 64);
    __shared__ int ws[4];
    if ((t & 63) == 0) ws[t >> 6] = s;
    __syncthreads();
    if (t == 0) bsum[b] = ws[0] + ws[1] + ws[2] + ws[3];
}

__global__ void k_scan2(const int* __restrict__ bsum, int* __restrict__ bbase,
                        int* __restrict__ offsets) {
    int lane = threadIdx.x;   // 64 threads
    int v0 = (lane < SCAN_B) ? bsum[lane] : 0;
    int v1 = (64 + lane < SCAN_B) ? bsum[64 + lane] : 0;
    int s0 = v0;
    #pragma unroll
    for (int d = 1; d < 64; d <<= 1) { int t = __shfl_up(s0, d, 64); if (lane >= d) s0 += t; }
    int tot0 = __shfl(s0, 63, 64);
    int s1 = v1;
    #pragma unroll
    for (int d = 1; d < 64; d <<= 1) { int t = __shfl_up(s1, d, 64); if (lane >= d) s1 += t; }
    int tot1 = __shfl(s1, 63, 64);
    if (lane < SCAN_B) bbase[lane] = s0 - v0;
    if (64 + lane < SCAN_B) bbase[64 + lane] = tot0 + s1 - v1;
    if (lane == 0) offsets[N_NODES] = tot0 + tot1;
}

__global__ void k_scan3(const int* __restrict__ counts, const int* __restrict__ bbase,
                        int* __restrict__ offsets, int* __restrict__ cursor) {
    int t = threadIdx.x, b = blockIdx.x;
    int lane = t & 63, wid = t >> 6;
    int i = b * 256 + t;
    int v = (i < N_NODES) ? counts[i] : 0;
    int s = v;
    #pragma unroll
    for (int d = 1; d < 64; d <<= 1) { int u = __shfl_up(s, d, 64); if (lane >= d) s += u; }
    __shared__ int ws[4];
    if (lane == 63) ws[wid] = s;
    __syncthreads();
    int wb = 0;
    #pragma unroll
    for (int w = 0; w < 3; ++w) if (w < wid) wb += ws[w];
    int excl = bbase[b] + wb + (s - v);
    if (i < N_NODES) { offsets[i] = excl; cursor[i] = excl; }
}

__global__ void k_scatter(const int* __restrict__ src, const int* __restrict__ dst,
                          int* __restrict__ cursor, int* __restrict__ ssrc) {
    int e = blockIdx.x * blockDim.x + threadIdx.x;
    if (e < N_EDGES) {
        int d = dst[e];
        int p = atomicAdd(&cursor[d], 1);
        ssrc[p] = src[e];
    }
}

// ---------------- Wt = W_ae^T in bf16, K padded to 2048 ----------------

__global__ void k_wt(const float* __restrict__ W, unsigned short* __restrict__ Wt) {
    int idx = blockIdx.x * 256 + threadIdx.x;
    int n = idx >> 11;
    int k = idx & 2047;
    float v = (k < IN_F) ? W[(size_t)k * C_OUT + n] : 0.f;
    Wt[(size_t)n * KPAD + k] = f2bf(v);
}

// ---------------- h = x @ W_ae + b_ae  (bf16 MFMA) ----------------

__global__ __launch_bounds__(256) void k_gemm_h(
    const float* __restrict__ x, const unsigned short* __restrict__ Wt,
    const float* __restrict__ b, float* __restrict__ h) {
    __shared__ unsigned short Asw[32 * 64];
    __shared__ unsigned short Bsw[64 * 64];
    int t = threadIdx.x;
    int lane = t & 63, wid = t >> 6;
    int wr = wid >> 1, wc = wid & 1;
    int row0 = blockIdx.x * 32;

    int a_row = t & 31, a_half = t >> 5;
    int b_n = t >> 2, b_kq = t & 3;

    int rA = wr * 16 + (lane & 15);
    int kchunk = lane >> 4;
    f32x4 acc0 = {0.f, 0.f, 0.f, 0.f}, acc1 = {0.f, 0.f, 0.f, 0.f};

    for (int k0 = 0; k0 < KPAD; k0 += 64) {
        {
            uint4 wv = {0u, 0u, 0u, 0u};
            int kbase = k0 + a_half * 8;
            if (kbase < IN_F) {
                const float* src = &x[(size_t)(row0 + a_row) * IN_F + kbase];
                float4 f0 = *(const float4*)src;
                float4 f1 = *(const float4*)(src + 4);
                wv.x = (unsigned)f2bf(f0.x) | ((unsigned)f2bf(f0.y) << 16);
                wv.y = (unsigned)f2bf(f0.z) | ((unsigned)f2bf(f0.w) << 16);
                wv.z = (unsigned)f2bf(f1.x) | ((unsigned)f2bf(f1.y) << 16);
                wv.w = (unsigned)f2bf(f1.z) | ((unsigned)f2bf(f1.w) << 16);
            }
            int slot = a_half ^ (a_row & 7);
            *(uint4*)((char*)Asw + a_row * 128 + slot * 16) = wv;
        }
        {
            const uint4* src = (const uint4*)&Wt[(size_t)b_n * KPAD + k0 + b_kq * 16];
            uint4 w0 = src[0], w1 = src[1];
            int s0 = (b_kq * 2) ^ (b_n & 7);
            int s1 = (b_kq * 2 + 1) ^ (b_n & 7);
            *(uint4*)((char*)Bsw + b_n * 128 + s0 * 16) = w0;
            *(uint4*)((char*)Bsw + b_n * 128 + s1 * 16) = w1;
        }
        __syncthreads();
        #pragma unroll
        for (int ks = 0; ks < 2; ++ks) {
            int aslot = (ks * 4 + kchunk) ^ (rA & 7);
            bf16x8 af = *(bf16x8*)((char*)Asw + rA * 128 + aslot * 16);
            {
                int cb = wc * 32 + (lane & 15);
                int bslot = (ks * 4 + kchunk) ^ (cb & 7);
                bf16x8 bfr = *(bf16x8*)((char*)Bsw + cb * 128 + bslot * 16);
                acc0 = __builtin_amdgcn_mfma_f32_16x16x32_bf16(af, bfr, acc0, 0, 0, 0);
            }
            {
                int cb = wc * 32 + 16 + (lane & 15);
                int bslot = (ks * 4 + kchunk) ^ (cb & 7);
                bf16x8 bfr = *(bf16x8*)((char*)Bsw + cb * 128 + bslot * 16);
                acc1 = __builtin_amdgcn_mfma_f32_16x16x32_bf16(af, bfr, acc1, 0, 0, 0);
            }
        }
        __syncthreads();
    }
    int ci = (lane >> 4) * 4;
    int cj = lane & 15;
    #pragma unroll
    for (int nt = 0; nt < 2; ++nt) {
        f32x4 a = nt ? acc1 : acc0;
        int col = wc * 32 + nt * 16 + cj;
        float bb = b[col];
        #pragma unroll
        for (int r = 0; r < 4; ++r) {
            int grow = row0 + wr * 16 + ci + r;
            h[(size_t)grow * C_OUT + col] = a[r] + bb;
        }
    }
}

// ---------------- xl (fp16) | xr (fp32) = h @ [Wl|Wr] + [bl|br] ----------------

__global__ __launch_bounds__(256) void k_xlxr2(
    const float* __restrict__ h, const float* __restrict__ Wl, const float* __restrict__ bl,
    const float* __restrict__ Wr, const float* __restrict__ br,
    unsigned short* __restrict__ xlh, float* __restrict__ xr) {
    __shared__ float hs[64][68];
    __shared__ float Ws[64][128];
    int t = threadIdx.x;
    int mb = blockIdx.x >> 2, nb = blockIdx.x & 3;
    int node0 = mb * 64;
    const float* Wsrc = (nb < 2) ? (Wl + nb * 128) : (Wr + (nb - 2) * 128);
    const float* bsrc = (nb < 2) ? (bl + nb * 128) : (br + (nb - 2) * 128);

    {
        int row = t >> 2, q = t & 3;
        int gnode = node0 + row; if (gnode >= N_NODES) gnode = N_NODES - 1;
        const float4* src = (const float4*)&h[(size_t)gnode * C_OUT + q * 16];
        *(float4*)&hs[row][q * 16 + 0]  = src[0];
        *(float4*)&hs[row][q * 16 + 4]  = src[1];
        *(float4*)&hs[row][q * 16 + 8]  = src[2];
        *(float4*)&hs[row][q * 16 + 12] = src[3];
    }
    {
        #pragma unroll
        for (int i = 0; i < 8; ++i) {
            int f = t + i * 256;
            int k = f >> 5, c4 = (f & 31) << 2;
            *(float4*)&Ws[k][c4] = *(const float4*)&Wsrc[(size_t)k * HC + c4];
        }
    }
    __syncthreads();

    int tr = t >> 5;
    int tc = t & 31;
    float4 acc[8];
    float4 bv = *(const float4*)&bsrc[tc * 4];
    #pragma unroll
    for (int r = 0; r < 8; ++r) acc[r] = bv;

    for (int k4 = 0; k4 < 64; k4 += 4) {
        float4 w0 = *(float4*)&Ws[k4 + 0][tc * 4];
        float4 w1 = *(float4*)&Ws[k4 + 1][tc * 4];
        float4 w2 = *(float4*)&Ws[k4 + 2][tc * 4];
        float4 w3 = *(float4*)&Ws[k4 + 3][tc * 4];
        #pragma unroll
        for (int r = 0; r < 8; ++r) {
            float4 a = *(float4*)&hs[tr * 8 + r][k4];
            acc[r].x += a.x * w0.x + a.y * w1.x + a.z * w2.x + a.w * w3.x;
            acc[r].y += a.x * w0.y + a.y * w1.y + a.z * w2.y + a.w * w3.y;
            acc[r].z += a.x * w0.z + a.y * w1.z + a.z * w2.z + a.w * w3.z;
            acc[r].w += a.x * w0.w + a.y * w1.w + a.z * w2.w + a.w * w3.w;
        }
    }
    #pragma unroll
    for (int r = 0; r < 8; ++r) {
        int gnode = node0 + tr * 8 + r;
        if (gnode < N_NODES) {
            if (nb < 2) {
                h2 lo = { (_Float16)acc[r].x, (_Float16)acc[r].y };
                h2 hi = { (_Float16)acc[r].z, (_Float16)acc[r].w };
                uint2 o = { __builtin_bit_cast(unsigned, lo),
                            __builtin_bit_cast(unsigned, hi) };
                *(uint2*)&xlh[(size_t)gnode * HC + nb * 128 + tc * 4] = o;
            } else {
                *(float4*)&xr[(size_t)gnode * HC + (nb - 2) * 128 + tc * 4] = acc[r];
            }
        }
    }
}

// ---------------- fused attention + linear + residual + LayerNorm ----------------
// 4 edges/wave (sub = lane>>4); lane covers 16 channels (sl*16..) as 8 fp16 pairs.
// 2-deep register software pipeline: edge B's gather issues before edge A computes.

__global__ __launch_bounds__(256) void k_attn(
    const unsigned short* __restrict__ xlh, const float* __restrict__ xr,
    const float* __restrict__ h, const int* __restrict__ offsets,
    const int* __restrict__ ssrc, const float* __restrict__ att,
    const float* __restrict__ b_conv, const float* __restrict__ W_lin,
    const float* __restrict__ b_lin, const float* __restrict__ ln_w,
    const float* __restrict__ ln_b, float* __restrict__ out) {
    __shared__ float sh[4][HC];
    int wid = threadIdx.x >> 6, lane = threadIdx.x & 63;
    int node = blockIdx.x * 4 + wid;
    int sub = lane >> 4;     // edge slot 0..3
    int sl  = lane & 15;     // channel group
    int c0  = sl * 16;

    const h2 z2  = { (_Float16)0.f, (_Float16)0.f };
    const h2 ns2 = { (_Float16)NEG, (_Float16)NEG };

    h2 xr2[8], at2[8];
    #pragma unroll
    for (int i = 0; i < 4; ++i) {
        float4 t4 = *(const float4*)&xr[(size_t)node * HC + c0 + i * 4];
        xr2[i*2+0] = h2{ (_Float16)t4.x, (_Float16)t4.y };
        xr2[i*2+1] = h2{ (_Float16)t4.z, (_Float16)t4.w };
        float4 a4 = *(const float4*)&att[c0 + i * 4];
        at2[i*2+0] = h2{ (_Float16)a4.x, (_Float16)a4.y };
        at2[i*2+1] = h2{ (_Float16)a4.z, (_Float16)a4.w };
    }
    h2 acc2[8];
    #pragma unroll
    for (int i = 0; i < 8; ++i) acc2[i] = z2;
    float denom = 0.f;

    auto load_edge = [&](int j, uint4& w0, uint4& w1) {
        const uint4* rp = (const uint4*)&xlh[(size_t)j * HC + c0];
        w0 = rp[0]; w1 = rp[1];
    };
    auto compute_edge = [&](uint4 w0, uint4 w1, bool valid) {
        h2 x2[8];
        x2[0] = __builtin_bit_cast(h2, w0.x); x2[1] = __builtin_bit_cast(h2, w0.y);
        x2[2] = __builtin_bit_cast(h2, w0.z); x2[3] = __builtin_bit_cast(h2, w0.w);
        x2[4] = __builtin_bit_cast(h2, w1.x); x2[5] = __builtin_bit_cast(h2, w1.y);
        x2[6] = __builtin_bit_cast(h2, w1.z); x2[7] = __builtin_bit_cast(h2, w1.w);
        h2 p2 = z2;
        #pragma unroll
        for (int i = 0; i < 8; ++i) {
            h2 g  = x2[i] + xr2[i];
            h2 gs = g * ns2;
            g = __builtin_elementwise_max(g, gs);   // leaky: max(g, 0.2g), exact
            p2 += g * at2[i];
        }
        float p = (float)p2.x + (float)p2.y;
        p += __shfl_xor(p, 1); p += __shfl_xor(p, 2);   // 4 lanes = one head
        float ex = valid ? __expf(p) : 0.f;             // logits O(1): no max shift
        denom += ex;
        h2 e2 = { (_Float16)ex, (_Float16)ex };
        #pragma unroll
        for (int i = 0; i < 8; ++i) acc2[i] += e2 * x2[i];
    };

    {   // self loop (counted once, slot 0)
        uint4 s0v, s1v;
        load_edge(node, s0v, s1v);
        compute_edge(s0v, s1v, sub == 0);
    }

    int s0 = offsets[node], s1 = offsets[node + 1];
    for (int base = s0; base < s1; base += 64) {
        int rem = s1 - base;
        int cnt = rem < 64 ? rem : 64;
        int jv = (base + lane < s1) ? ssrc[base + lane] : 0;
        int niter = (cnt + 3) >> 2;
        uint4 a0, a1, b0, b1;
        int jA = __shfl(jv, sub, 64);
        load_edge(jA, a0, a1);
        for (int it = 0; it < niter; it += 2) {
            int eB = ((it + 1) << 2) + sub;
            int jB = __shfl(jv, eB & 63, 64);
            load_edge(jB, b0, b1);                    // prefetch B under A's compute
            compute_edge(a0, a1, ((it << 2) + sub) < cnt);
            int eA2 = ((it + 2) << 2) + sub;
            int jA2 = __shfl(jv, eA2 & 63, 64);
            load_edge(jA2, a0, a1);                   // prefetch next A under B
            compute_edge(b0, b1, eB < cnt);
        }
    }

    // unpack to fp32, reduce over the 4 edge slots
    float accf[16];
    #pragma unroll
    for (int i = 0; i < 8; ++i) {
        accf[2*i]   = (float)acc2[i].x;
        accf[2*i+1] = (float)acc2[i].y;
    }
    #pragma unroll
    for (int i = 0; i < 16; ++i) {
        accf[i] += __shfl_xor(accf[i], 16);
        accf[i] += __shfl_xor(accf[i], 32);
    }
    denom += __shfl_xor(denom, 16);
    denom += __shfl_xor(denom, 32);

    float inv = 1.f / denom;
    if (sub == 0) {
        #pragma unroll
        for (int i = 0; i < 4; ++i) {
            float4 bc = *(const float4*)&b_conv[c0 + i * 4];
            float4 o = { accf[i*4+0] * inv + bc.x, accf[i*4+1] * inv + bc.y,
                         accf[i*4+2] * inv + bc.z, accf[i*4+3] * inv + bc.w };
            *(float4*)&sh[wid][c0 + i * 4] = o;
        }
    }
    __syncthreads();

    // a = relu(ov @ W_lin + b_lin); lane = output channel
    float s = b_lin[lane];
    #pragma unroll 8
    for (int k = 0; k < HC; k += 4) {
        float4 o4 = *(float4*)&sh[wid][k];
        s += o4.x * W_lin[(k + 0) * C_OUT + lane];
        s += o4.y * W_lin[(k + 1) * C_OUT + lane];
        s += o4.z * W_lin[(k + 2) * C_OUT + lane];
        s += o4.w * W_lin[(k + 3) * C_OUT + lane];
    }
    float a = s > 0.f ? s : 0.f;
    float y = a + h[(size_t)node * C_OUT + lane];

    float m = y;
    m += __shfl_xor(m, 1);  m += __shfl_xor(m, 2);  m += __shfl_xor(m, 4);
    m += __shfl_xor(m, 8);  m += __shfl_xor(m, 16); m += __shfl_xor(m, 32);
    m *= (1.f / 64.f);
    float d = y - m;
    float v2 = d * d;
    v2 += __shfl_xor(v2, 1);  v2 += __shfl_xor(v2, 2);  v2 += __shfl_xor(v2, 4);
    v2 += __shfl_xor(v2, 8);  v2 += __shfl_xor(v2, 16); v2 += __shfl_xor(v2, 32);
    v2 *= (1.f / 64.f);
    out[(size_t)node * C_OUT + lane] = ln_w[lane] * d * rsqrtf(v2 + 1e-12f) + ln_b[lane];
}

// ---------------- launch ----------------

extern "C" void kernel_launch(void* const* d_in, const int* in_sizes, int n_in,
                              void* d_out, int out_size, void* d_ws, size_t ws_size,
                              hipStream_t stream) {
    const float* x     = (const float*)d_in[0];
    const int*   ei    = (const int*)  d_in[1];
    const float* W_ae  = (const float*)d_in[2];
    const float* b_ae  = (const float*)d_in[3];
    const float* Wl    = (const float*)d_in[4];
    const float* bl    = (const float*)d_in[5];
    const float* Wr    = (const float*)d_in[6];
    const float* br    = (const float*)d_in[7];
    const float* att   = (const float*)d_in[8];
    const float* b_conv= (const float*)d_in[9];
    const float* W_lin = (const float*)d_in[10];
    const float* b_lin = (const float*)d_in[11];
    const float* ln_w  = (const float*)d_in[12];
    const float* ln_b  = (const float*)d_in[13];
    float* out = (float*)d_out;
    const int* src = ei;
    const int* dst = ei + N_EDGES;

    char* ws = (char*)d_ws;
    size_t off = 0;
    auto alloc = [&](size_t bytes) {
        void* p = ws + off;
        off = (off + bytes + 255) & ~(size_t)255;
        return p;
    };
    float* h       = (float*)alloc((size_t)N_NODES * C_OUT * 4);
    unsigned short* xlh = (unsigned short*)alloc((size_t)N_NODES * HC * 2);
    float* xr      = (float*)alloc((size_t)N_NODES * HC * 4);
    int*   counts  = (int*)  alloc((size_t)N_NODES * 4);
    int*   offsets = (int*)  alloc((size_t)(N_NODES + 1) * 4);
    int*   cursor  = (int*)  alloc((size_t)N_NODES * 4);
    int*   ssrc    = (int*)  alloc((size_t)N_EDGES * 4);
    unsigned short* Wt = (unsigned short*)alloc((size_t)C_OUT * KPAD * 2);
    int*   bsum    = (int*)  alloc((size_t)SCAN_B * 4);
    int*   bbase   = (int*)  alloc((size_t)SCAN_B * 4);

    (void)hipMemsetAsync(counts, 0, (size_t)N_NODES * 4, stream);
    k_hist   <<<(N_EDGES + 255) / 256, 256, 0, stream>>>(dst, counts);
    k_scan1  <<<SCAN_B, 256, 0, stream>>>(counts, bsum);
    k_scan2  <<<1, 64, 0, stream>>>(bsum, bbase, offsets);
    k_scan3  <<<SCAN_B, 256, 0, stream>>>(counts, bbase, offsets, cursor);
    k_scatter<<<(N_EDGES + 255) / 256, 256, 0, stream>>>(src, dst, cursor, ssrc);
    k_wt     <<<(C_OUT * KPAD) / 256, 256, 0, stream>>>(W_ae, Wt);
    k_gemm_h <<<N_NODES / 32, 256, 0, stream>>>(x, Wt, b_ae, h);
    k_xlxr2  <<<((N_NODES + 63) / 64) * 4, 256, 0, stream>>>(h, Wl, bl, Wr, br, xlh, xr);
    k_attn   <<<N_NODES / 4, 256, 0, stream>>>(xlh, xr, h, offsets, ssrc, att,
                                               b_conv, W_lin, b_lin, ln_w, ln_b, out);
}